// Round 20
// baseline (842.072 us; speedup 1.0000x reference)
//
#include <hip/hip_runtime.h>

typedef __attribute__((ext_vector_type(8))) short short8;
typedef __attribute__((ext_vector_type(4))) float f32x4;

#define B_SZ 8192
#define H_SZ 1024
#define R_SZ 16

__device__ __forceinline__ unsigned short f2bf(float f) {
  union { float f; unsigned u; } v; v.f = f;
  unsigned u = v.u + 0x7FFFu + ((v.u >> 16) & 1u);
  return (unsigned short)(u >> 16);
}

// ------------- transpose + convert: src[rows][cols] f32 -> dst[cols][rows] bf16 -------------
__global__ __launch_bounds__(256) void tck_transpose(const float* __restrict__ src,
                                                     unsigned short* __restrict__ dst,
                                                     int rows, int cols) {
  __shared__ float t[32][33];
  size_t zoff = (size_t)blockIdx.z * (size_t)rows * cols;
  int c0 = blockIdx.x * 32, r0 = blockIdx.y * 32;
  int tx = threadIdx.x, ty = threadIdx.y;
#pragma unroll
  for (int i = 0; i < 4; ++i)
    t[ty + 8 * i][tx] = src[zoff + (size_t)(r0 + ty + 8 * i) * cols + c0 + tx];
  __syncthreads();
#pragma unroll
  for (int i = 0; i < 4; ++i)
    dst[zoff + (size_t)(c0 + ty + 8 * i) * rows + r0 + tx] = f2bf(t[tx][ty + 8 * i]);
}

// ------------- Wa [1024][16] f32 -> WaT [16][1024] f32 -------------
__global__ __launch_bounds__(256) void twk_transpose_wa(const float* __restrict__ Wa,
                                                        float* __restrict__ WaT) {
  int t = blockIdx.x * 256 + threadIdx.x;  // 16384 total
  int h = t >> 4, r = t & 15;
  WaT[r * H_SZ + h] = Wa[t];
}

// ------------- gate + xb emit -------------
__global__ __launch_bounds__(256) void gk_gate(const float* __restrict__ x,
                                               const float* __restrict__ WaT,
                                               const float* __restrict__ ba,
                                               const float* __restrict__ Wc,
                                               const float* __restrict__ bc,
                                               float* __restrict__ comb,
                                               float* __restrict__ conf,
                                               unsigned short* __restrict__ xb) {
  int b = blockIdx.x * 4 + (threadIdx.x >> 6);
  int l = threadIdx.x & 63;
  const float* xr = x + (size_t)b * H_SZ;
  unsigned short* xbr = xb + (size_t)b * H_SZ;
  float xv[16];
#pragma unroll
  for (int j = 0; j < 16; ++j) xv[j] = xr[l + 64 * j];
#pragma unroll
  for (int j = 0; j < 16; ++j) xbr[l + 64 * j] = f2bf(xv[j]);
  float la[16], lcf[16];
#pragma unroll
  for (int r = 0; r < 16; ++r) {
    float sa = 0.f, sc = 0.f;
#pragma unroll
    for (int j = 0; j < 16; ++j) {
      int h = l + 64 * j;
      sa += xv[j] * WaT[r * H_SZ + h];
      sc += xv[j] * Wc[r * H_SZ + h];
    }
#pragma unroll
    for (int off = 32; off > 0; off >>= 1) {
      sa += __shfl_xor(sa, off);
      sc += __shfl_xor(sc, off);
    }
    la[r] = sa + ba[r];
    lcf[r] = sc + bc[r];
  }
  float mx = la[0];
#pragma unroll
  for (int r = 1; r < 16; ++r) mx = fmaxf(mx, la[r]);
  float se = 0.f;
#pragma unroll
  for (int r = 0; r < 16; ++r) { la[r] = expf(la[r] - mx); se += la[r]; }
  float cb[16]; float cs = 0.f;
#pragma unroll
  for (int r = 0; r < 16; ++r) {
    float cf = 1.f / (1.f + expf(-lcf[r]));
    lcf[r] = cf;
    cb[r] = (la[r] / se) * cf;
    cs += cb[r];
  }
  float inv = 1.f / (cs + 1e-8f);
  if (l < 16) {
    float cv = 0.f, qv = 0.f;
#pragma unroll
    for (int r = 0; r < 16; ++r)
      if (r == l) { cv = lcf[r]; qv = cb[r] * inv; }
    conf[b * 16 + l] = cv;
    comb[b * 16 + l] = qv;
  }
}

// ------------- out += partial (vectorized) -------------
__global__ __launch_bounds__(256) void redk_add(float* __restrict__ out,
                                                const float* __restrict__ p1) {
  size_t i = ((size_t)blockIdx.x * 256 + threadIdx.x) * 4;
  float4 a = *(const float4*)(out + i);
  float4 b = *(const float4*)(p1 + i);
  a.x += b.x; a.y += b.y; a.z += b.z; a.w += b.w;
  *(float4*)(out + i) = a;
}

// async global->LDS, 16B per lane; LDS dest wave-uniform base (+ lane*16 by HW)
__device__ __forceinline__ void gload16(const unsigned short* g, const unsigned short* l) {
  __builtin_amdgcn_global_load_lds(
      (const __attribute__((address_space(1))) unsigned int*)g,
      (__attribute__((address_space(3))) unsigned int*)(unsigned short*)l, 16, 0, 0);
}

// ================= g8r_gemm: 256x256 8-phase, m201 protocol (R10/R12-verified body) ========
// Sync/phase/vmcnt structure byte-identical to the verified kernel; only staging ADDRESSES
// and epilogue differ by MODE.
// MODE 0 (GEMM1): A = xb (lda), B = W1T (ldb) as before.
//   Epilogue: Hp stored PER-RULE: Hp[r_local][8192][1024]  (2KB row stride).
// MODE 2 (GEMM2, split-K z in {0,1}): operands PER-RULE-blocked, uniform 2KB stride:
//   A-tile (k-slice kt) = Hp + (kt>>4)*B*H + row*1024 + (kt&15)*64
//   B-tile              = W2T + (kt>>4)*H*H + row*1024 + (kt&15)*64
//   split-K offset: += z*(K/1024) rule blocks. Grid x = m-block (same-A sharers on one XCD).
//   z=0 -> Out = acc (+ sum_r comb*b2 if !accum, else + Out); z=1 -> Out2 (+ Out2 if accum).
#define RDA(DST, MH)                                                                   \
  _Pragma("unroll") for (int c = 0; c < 2; ++c)                                        \
  _Pragma("unroll") for (int f = 0; f < 4; ++f) {                                      \
    int ra = (MH) * 128 + wm * 64 + f * 16 + lc;                                       \
    DST[c][f] = *(const short8*)(bufp + ra * 64 + (((c * 4 + lr) ^ (ra & 7)) * 8));    \
  }
#define RDB(DST, NH)                                                                   \
  _Pragma("unroll") for (int c = 0; c < 2; ++c)                                        \
  _Pragma("unroll") for (int g = 0; g < 2; ++g) {                                      \
    int rb = (NH) * 128 + wn * 32 + g * 16 + lc;                                       \
    DST[c][g] = *(const short8*)(bufp + ABM + rb * 64 + (((c * 4 + lr) ^ (rb & 7)) * 8)); \
  }
#define MF(AS, BS, MH, NH)                                                             \
  __builtin_amdgcn_s_setprio(1);                                                       \
  _Pragma("unroll") for (int c = 0; c < 2; ++c)                                        \
  _Pragma("unroll") for (int f = 0; f < 4; ++f)                                        \
  _Pragma("unroll") for (int g = 0; g < 2; ++g)                                        \
    acc[(MH) * 4 + f][(NH) * 2 + g] = __builtin_amdgcn_mfma_f32_16x16x32_bf16(         \
        AS[c][f], BS[c][g], acc[(MH) * 4 + f][(NH) * 2 + g], 0, 0, 0);                 \
  __builtin_amdgcn_s_setprio(0);
#define LGKM0                                                                          \
  asm volatile("s_waitcnt lgkmcnt(0)" ::: "memory");                                   \
  __builtin_amdgcn_sched_barrier(0);

template <int MODE>
__global__ __launch_bounds__(512, 1) void g8r_gemm(
    const unsigned short* __restrict__ A, int lda,
    const unsigned short* __restrict__ Bm, int ldb, int K,
    unsigned short* __restrict__ Hp, int ldh,
    const float* __restrict__ b1v,
    float* __restrict__ Out,
    const float* __restrict__ b2v,
    const float* __restrict__ comb,
    int r_base, int accum,
    float* __restrict__ Out2) {
  constexpr int ABM = 256 * 64;              // A-tile elems (32KB)
  constexpr int BUFE = 2 * ABM;              // A+B per buffer (64KB)
  constexpr size_t ARULE = (size_t)B_SZ * H_SZ;  // Hp rule-block elems
  constexpr size_t BRULE = (size_t)H_SZ * H_SZ;  // W2T rule-block elems
  __shared__ unsigned short smem[2 * BUFE];  // 128KB

  const int tid = threadIdx.x;
  const int lane = tid & 63;
  const int wid = tid >> 6;
  const int wm = wid >> 2, wn = wid & 3;
  const int lr = lane >> 4, lc = lane & 15;
  const int bn0 = (MODE == 2 ? blockIdx.y : blockIdx.x) * 256;
  const int bm0 = (MODE == 2 ? blockIdx.x : blockIdx.y) * 256;
  const int KT = K >> 6;                     // >= 2
  if (MODE == 2) {                           // split-K: offset by z*(K/1024) rule blocks
    A += (size_t)blockIdx.z * (size_t)(K >> 10) * ARULE;
    Bm += (size_t)blockIdx.z * (size_t)(K >> 10) * BRULE;
  }

  f32x4 acc[8][4];
#pragma unroll
  for (int i = 0; i < 8; ++i)
#pragma unroll
    for (int j = 0; j < 4; ++j) acc[i][j] = {0.f, 0.f, 0.f, 0.f};

  auto stageA = [&](int buf, int kt, int h) {
#pragma unroll
    for (int q = 0; q < 2; ++q) {
      int idx = q * 512 + tid;
      int row = h * 128 + (idx >> 3);
      int ck = (idx & 7) ^ (row & 7);
      const unsigned short* src;
      if (MODE == 2)
        src = A + (size_t)(kt >> 4) * ARULE + (size_t)(bm0 + row) * H_SZ +
              (kt & 15) * 64 + ck * 8;
      else
        src = A + (size_t)(bm0 + row) * lda + kt * 64 + ck * 8;
      gload16(src, smem + buf * BUFE + h * 8192 + (q * 512 + (tid & ~63)) * 8);
    }
  };
  auto stageB = [&](int buf, int kt, int h) {
#pragma unroll
    for (int q = 0; q < 2; ++q) {
      int idx = q * 512 + tid;
      int row = h * 128 + (idx >> 3);
      int ck = (idx & 7) ^ (row & 7);
      const unsigned short* src;
      if (MODE == 2)
        src = Bm + (size_t)(kt >> 4) * BRULE + (size_t)(bn0 + row) * H_SZ +
              (kt & 15) * 64 + ck * 8;
      else
        src = Bm + (size_t)(bn0 + row) * ldb + kt * 64 + ck * 8;
      gload16(src, smem + buf * BUFE + ABM + h * 8192 + (q * 512 + (tid & ~63)) * 8);
    }
  };

  stageA(0, 0, 0); stageB(0, 0, 0); stageB(0, 0, 1); stageA(0, 0, 1);
  stageA(1, 1, 0); stageB(1, 1, 0); stageB(1, 1, 1);
  asm volatile("s_waitcnt vmcnt(6)" ::: "memory");  // tile 0 resident
  __builtin_amdgcn_s_barrier();

  for (int t = 0; t < KT; ++t) {
    const unsigned short* bufp = smem + (t & 1) * BUFE;
    const int nb = (t & 1) ^ 1;
    const int cb = (t & 1);
    short8 a0[2][4], a1[2][4], b0[2][2], b1h[2][2];

    RDA(a0, 0)
    RDB(b0, 0)
    if (t + 1 < KT) stageA(nb, t + 1, 1);
    __builtin_amdgcn_s_barrier();
    LGKM0
    MF(a0, b0, 0, 0)
    __builtin_amdgcn_s_barrier();

    RDB(b1h, 1)
    if (t + 2 < KT) stageA(cb, t + 2, 0);
    __builtin_amdgcn_s_barrier();
    LGKM0
    MF(a0, b1h, 0, 1)
    __builtin_amdgcn_s_barrier();

    RDA(a1, 1)
    if (t + 2 < KT) stageB(cb, t + 2, 0);
    __builtin_amdgcn_s_barrier();
    LGKM0
    MF(a1, b1h, 1, 1)
    __builtin_amdgcn_s_barrier();

    if (t + 2 < KT) stageB(cb, t + 2, 1);
    __builtin_amdgcn_s_barrier();
    MF(a1, b0, 1, 0)
    asm volatile("s_waitcnt vmcnt(6)" ::: "memory");
    __builtin_amdgcn_s_barrier();
  }

  // epilogue: C/D layout col=lane&15, row=(lane>>4)*4+reg
#pragma unroll
  for (int i = 0; i < 8; ++i) {
#pragma unroll
    for (int j = 0; j < 4; ++j) {
      int m0 = bm0 + (i >> 2) * 128 + wm * 64 + (i & 3) * 16 + lr * 4;
      int n = bn0 + (j >> 1) * 128 + wn * 32 + (j & 1) * 16 + lc;
      f32x4 a = acc[i][j];
      if (MODE == 0) {
        int rl = n >> 10;                 // local rule
        int r = r_base + rl;              // global rule (bias/comb)
        int d = n & 1023;
        float bias = b1v[r * H_SZ + d];
#pragma unroll
        for (int jj = 0; jj < 4; ++jj) {
          float v = fmaxf(a[jj] + bias, 0.f) * comb[(size_t)(m0 + jj) * 16 + r];
          Hp[(size_t)rl * ARULE + (size_t)(m0 + jj) * H_SZ + d] = f2bf(v);
        }
      } else {  // MODE 2
        float* dst = blockIdx.z ? Out2 : Out;
#pragma unroll
        for (int jj = 0; jj < 4; ++jj) {
          size_t row = (size_t)(m0 + jj);
          float v = a[jj];
          if (accum) {
            v += dst[row * H_SZ + n];
          } else if (blockIdx.z == 0) {
            float bs = 0.f;
#pragma unroll
            for (int r = 0; r < 16; ++r)
              bs += comb[row * 16 + r] * b2v[r * H_SZ + n];
            v += bs;
          }
          dst[row * H_SZ + n] = v;
        }
      }
    }
  }
}
#undef RDA
#undef RDB
#undef MF
#undef LGKM0

extern "C" void kernel_launch(void* const* d_in, const int* in_sizes, int n_in,
                              void* d_out, int out_size, void* d_ws, size_t ws_size,
                              hipStream_t stream) {
  if (n_in < 9) return;
  const float* x  = (const float*)d_in[0];
  const float* Wa = (const float*)d_in[1];
  const float* ba = (const float*)d_in[2];
  const float* W1 = (const float*)d_in[3];
  const float* b1 = (const float*)d_in[4];
  const float* W2 = (const float*)d_in[5];
  const float* b2 = (const float*)d_in[6];
  const float* Wc = (const float*)d_in[7];
  const float* bc = (const float*)d_in[8];

  float* out = (float*)d_out;
  float* conf = out + (size_t)B_SZ * H_SZ;

  char* w = (char*)d_ws;
  unsigned short* xb = (unsigned short*)w;  w += (size_t)B_SZ * H_SZ * 2;
  unsigned short* W1T = (unsigned short*)w; w += (size_t)R_SZ * H_SZ * H_SZ * 2;
  unsigned short* W2T = (unsigned short*)w; w += (size_t)R_SZ * H_SZ * H_SZ * 2;
  float* comb = (float*)w;                  w += (size_t)B_SZ * R_SZ * 4;
  float* WaT = (float*)w;                   w += (size_t)R_SZ * H_SZ * 4;
  unsigned short* Hp = (unsigned short*)w;
  size_t used = (size_t)(w - (char*)d_ws);

  // choose largest G (rules/group) such that Hp (per-rule blocks) + split-K
  // partial surface both fit (measured harness: G=8 fits)
  int G = 16;
  while (G > 1 &&
         used + (size_t)B_SZ * G * H_SZ * 2 + (size_t)B_SZ * H_SZ * 4 > ws_size)
    G >>= 1;
  if (used + (size_t)B_SZ * G * H_SZ * 2 + (size_t)B_SZ * H_SZ * 4 > ws_size)
    return;  // ws too small
  float* part1 = (float*)((char*)Hp + (size_t)B_SZ * G * H_SZ * 2);

  dim3 tb(32, 8);
  tck_transpose<<<dim3(32, 32, 16), tb, 0, stream>>>(W1, W1T, H_SZ, H_SZ);
  // W2 per-rule: W2T[r][o][d] = W2[r][d][o]  (2KB stride within each rule block)
  tck_transpose<<<dim3(32, 32, 16), tb, 0, stream>>>(W2, W2T, H_SZ, H_SZ);
  twk_transpose_wa<<<dim3(64), dim3(256), 0, stream>>>(Wa, WaT);
  gk_gate<<<dim3(B_SZ / 4), dim3(256), 0, stream>>>(x, WaT, ba, Wc, bc, comb, conf, xb);

  int ngroups = R_SZ / G;
  for (int g = 0; g < ngroups; ++g) {
    // GEMM1 (8-phase, verified): Hp[r_local][m][d] = comb * relu(x @ W1[rule] + b1)
    g8r_gemm<0><<<dim3(G * H_SZ / 256, B_SZ / 256), dim3(512), 0, stream>>>(
        xb, H_SZ,
        W1T + (size_t)g * G * H_SZ * H_SZ, H_SZ, H_SZ,
        Hp, 0, b1, nullptr, nullptr, comb, g * G, 0, nullptr);
    // GEMM2 (same 8-phase body, per-rule 2KB-stride operands, split-K=2, 256 blocks):
    g8r_gemm<2><<<dim3(B_SZ / 256, H_SZ / 256, 2), dim3(512), 0, stream>>>(
        Hp, 0,
        W2T + (size_t)g * G * H_SZ * H_SZ, 0, (G * H_SZ) / 2,
        nullptr, 0, nullptr, out, b2, comb, 0, (g > 0) ? 1 : 0, part1);
  }
  redk_add<<<dim3((B_SZ * H_SZ) / (256 * 4)), dim3(256), 0, stream>>>(out, part1);
}

// Round 21
// 697.746 us; speedup vs baseline: 1.2068x; 1.2068x over previous
//
#include <hip/hip_runtime.h>

typedef __attribute__((ext_vector_type(8))) short short8;
typedef __attribute__((ext_vector_type(4))) float f32x4;

#define B_SZ 8192
#define H_SZ 1024
#define R_SZ 16

__device__ __forceinline__ unsigned short f2bf(float f) {
  union { float f; unsigned u; } v; v.f = f;
  unsigned u = v.u + 0x7FFFu + ((v.u >> 16) & 1u);
  return (unsigned short)(u >> 16);
}

// ------------- transpose + convert: src[rows][cols] f32 -> dst[cols][rows] bf16 -------------
__global__ __launch_bounds__(256) void tck_transpose(const float* __restrict__ src,
                                                     unsigned short* __restrict__ dst,
                                                     int rows, int cols) {
  __shared__ float t[32][33];
  size_t zoff = (size_t)blockIdx.z * (size_t)rows * cols;
  int c0 = blockIdx.x * 32, r0 = blockIdx.y * 32;
  int tx = threadIdx.x, ty = threadIdx.y;
#pragma unroll
  for (int i = 0; i < 4; ++i)
    t[ty + 8 * i][tx] = src[zoff + (size_t)(r0 + ty + 8 * i) * cols + c0 + tx];
  __syncthreads();
#pragma unroll
  for (int i = 0; i < 4; ++i)
    dst[zoff + (size_t)(c0 + ty + 8 * i) * rows + r0 + tx] = f2bf(t[tx][ty + 8 * i]);
}

// ------------- Wa [1024][16] f32 -> WaT [16][1024] f32 -------------
__global__ __launch_bounds__(256) void twk_transpose_wa(const float* __restrict__ Wa,
                                                        float* __restrict__ WaT) {
  int t = blockIdx.x * 256 + threadIdx.x;  // 16384 total
  int h = t >> 4, r = t & 15;
  WaT[r * H_SZ + h] = Wa[t];
}

// ------------- gate + xb emit -------------
__global__ __launch_bounds__(256) void gk_gate(const float* __restrict__ x,
                                               const float* __restrict__ WaT,
                                               const float* __restrict__ ba,
                                               const float* __restrict__ Wc,
                                               const float* __restrict__ bc,
                                               float* __restrict__ comb,
                                               float* __restrict__ conf,
                                               unsigned short* __restrict__ xb) {
  int b = blockIdx.x * 4 + (threadIdx.x >> 6);
  int l = threadIdx.x & 63;
  const float* xr = x + (size_t)b * H_SZ;
  unsigned short* xbr = xb + (size_t)b * H_SZ;
  float xv[16];
#pragma unroll
  for (int j = 0; j < 16; ++j) xv[j] = xr[l + 64 * j];
#pragma unroll
  for (int j = 0; j < 16; ++j) xbr[l + 64 * j] = f2bf(xv[j]);
  float la[16], lcf[16];
#pragma unroll
  for (int r = 0; r < 16; ++r) {
    float sa = 0.f, sc = 0.f;
#pragma unroll
    for (int j = 0; j < 16; ++j) {
      int h = l + 64 * j;
      sa += xv[j] * WaT[r * H_SZ + h];
      sc += xv[j] * Wc[r * H_SZ + h];
    }
#pragma unroll
    for (int off = 32; off > 0; off >>= 1) {
      sa += __shfl_xor(sa, off);
      sc += __shfl_xor(sc, off);
    }
    la[r] = sa + ba[r];
    lcf[r] = sc + bc[r];
  }
  float mx = la[0];
#pragma unroll
  for (int r = 1; r < 16; ++r) mx = fmaxf(mx, la[r]);
  float se = 0.f;
#pragma unroll
  for (int r = 0; r < 16; ++r) { la[r] = expf(la[r] - mx); se += la[r]; }
  float cb[16]; float cs = 0.f;
#pragma unroll
  for (int r = 0; r < 16; ++r) {
    float cf = 1.f / (1.f + expf(-lcf[r]));
    lcf[r] = cf;
    cb[r] = (la[r] / se) * cf;
    cs += cb[r];
  }
  float inv = 1.f / (cs + 1e-8f);
  if (l < 16) {
    float cv = 0.f, qv = 0.f;
#pragma unroll
    for (int r = 0; r < 16; ++r)
      if (r == l) { cv = lcf[r]; qv = cb[r] * inv; }
    conf[b * 16 + l] = cv;
    comb[b * 16 + l] = qv;
  }
}

// async global->LDS, 16B per lane; LDS dest wave-uniform base (+ lane*16 by HW)
__device__ __forceinline__ void gload16(const unsigned short* g, const unsigned short* l) {
  __builtin_amdgcn_global_load_lds(
      (const __attribute__((address_space(1))) unsigned int*)g,
      (__attribute__((address_space(3))) unsigned int*)(unsigned short*)l, 16, 0, 0);
}

// ================= g1k_gemm8: 256x256 8-phase, m201 protocol (R10/R12-verified) =================
// Used for GEMM1 (compute-bound, operands L2/L3-hot). Body byte-identical to the verified kernel.
#define RDA(DST, MH)                                                                   \
  _Pragma("unroll") for (int c = 0; c < 2; ++c)                                        \
  _Pragma("unroll") for (int f = 0; f < 4; ++f) {                                      \
    int ra = (MH) * 128 + wm * 64 + f * 16 + lc;                                       \
    DST[c][f] = *(const short8*)(bufp + ra * 64 + (((c * 4 + lr) ^ (ra & 7)) * 8));    \
  }
#define RDB(DST, NH)                                                                   \
  _Pragma("unroll") for (int c = 0; c < 2; ++c)                                        \
  _Pragma("unroll") for (int g = 0; g < 2; ++g) {                                      \
    int rb = (NH) * 128 + wn * 32 + g * 16 + lc;                                       \
    DST[c][g] = *(const short8*)(bufp + ABM + rb * 64 + (((c * 4 + lr) ^ (rb & 7)) * 8)); \
  }
#define MF(AS, BS, MH, NH)                                                             \
  __builtin_amdgcn_s_setprio(1);                                                       \
  _Pragma("unroll") for (int c = 0; c < 2; ++c)                                        \
  _Pragma("unroll") for (int f = 0; f < 4; ++f)                                        \
  _Pragma("unroll") for (int g = 0; g < 2; ++g)                                        \
    acc[(MH) * 4 + f][(NH) * 2 + g] = __builtin_amdgcn_mfma_f32_16x16x32_bf16(         \
        AS[c][f], BS[c][g], acc[(MH) * 4 + f][(NH) * 2 + g], 0, 0, 0);                 \
  __builtin_amdgcn_s_setprio(0);
#define LGKM0                                                                          \
  asm volatile("s_waitcnt lgkmcnt(0)" ::: "memory");                                   \
  __builtin_amdgcn_sched_barrier(0);

template <int MODE>
__global__ __launch_bounds__(512, 1) void g1k_gemm8(
    const unsigned short* __restrict__ A, int lda,
    const unsigned short* __restrict__ Bm, int ldb, int K,
    unsigned short* __restrict__ Hp, int ldh,
    const float* __restrict__ b1v,
    float* __restrict__ Out,
    const float* __restrict__ b2v,
    const float* __restrict__ comb,
    int r_base, int accum) {
  constexpr int ABM = 256 * 64;              // A-tile elems (32KB)
  constexpr int BUFE = 2 * ABM;              // A+B per buffer (64KB)
  __shared__ unsigned short smem[2 * BUFE];  // 128KB

  const int tid = threadIdx.x;
  const int lane = tid & 63;
  const int wid = tid >> 6;
  const int wm = wid >> 2, wn = wid & 3;
  const int lr = lane >> 4, lc = lane & 15;
  const int bn0 = blockIdx.x * 256;
  const int bm0 = blockIdx.y * 256;
  const int KT = K >> 6;                     // >= 2

  f32x4 acc[8][4];
#pragma unroll
  for (int i = 0; i < 8; ++i)
#pragma unroll
    for (int j = 0; j < 4; ++j) acc[i][j] = {0.f, 0.f, 0.f, 0.f};

  auto stageA = [&](int buf, int kt, int h) {
#pragma unroll
    for (int q = 0; q < 2; ++q) {
      int idx = q * 512 + tid;
      int row = h * 128 + (idx >> 3);
      int ck = (idx & 7) ^ (row & 7);
      gload16(A + (size_t)(bm0 + row) * lda + kt * 64 + ck * 8,
              smem + buf * BUFE + h * 8192 + (q * 512 + (tid & ~63)) * 8);
    }
  };
  auto stageB = [&](int buf, int kt, int h) {
#pragma unroll
    for (int q = 0; q < 2; ++q) {
      int idx = q * 512 + tid;
      int row = h * 128 + (idx >> 3);
      int ck = (idx & 7) ^ (row & 7);
      gload16(Bm + (size_t)(bn0 + row) * ldb + kt * 64 + ck * 8,
              smem + buf * BUFE + ABM + h * 8192 + (q * 512 + (tid & ~63)) * 8);
    }
  };

  stageA(0, 0, 0); stageB(0, 0, 0); stageB(0, 0, 1); stageA(0, 0, 1);
  stageA(1, 1, 0); stageB(1, 1, 0); stageB(1, 1, 1);
  asm volatile("s_waitcnt vmcnt(6)" ::: "memory");  // tile 0 resident
  __builtin_amdgcn_s_barrier();

  for (int t = 0; t < KT; ++t) {
    const unsigned short* bufp = smem + (t & 1) * BUFE;
    const int nb = (t & 1) ^ 1;
    const int cb = (t & 1);
    short8 a0[2][4], a1[2][4], b0[2][2], b1h[2][2];

    RDA(a0, 0)
    RDB(b0, 0)
    if (t + 1 < KT) stageA(nb, t + 1, 1);
    __builtin_amdgcn_s_barrier();
    LGKM0
    MF(a0, b0, 0, 0)
    __builtin_amdgcn_s_barrier();

    RDB(b1h, 1)
    if (t + 2 < KT) stageA(cb, t + 2, 0);
    __builtin_amdgcn_s_barrier();
    LGKM0
    MF(a0, b1h, 0, 1)
    __builtin_amdgcn_s_barrier();

    RDA(a1, 1)
    if (t + 2 < KT) stageB(cb, t + 2, 0);
    __builtin_amdgcn_s_barrier();
    LGKM0
    MF(a1, b1h, 1, 1)
    __builtin_amdgcn_s_barrier();

    if (t + 2 < KT) stageB(cb, t + 2, 1);
    __builtin_amdgcn_s_barrier();
    MF(a1, b0, 1, 0)
    asm volatile("s_waitcnt vmcnt(6)" ::: "memory");
    __builtin_amdgcn_s_barrier();
  }

#pragma unroll
  for (int i = 0; i < 8; ++i) {
#pragma unroll
    for (int j = 0; j < 4; ++j) {
      int m0 = bm0 + (i >> 2) * 128 + wm * 64 + (i & 3) * 16 + lr * 4;
      int n = bn0 + (j >> 1) * 128 + wn * 32 + (j & 1) * 16 + lc;
      f32x4 a = acc[i][j];
      if (MODE == 0) {
        int r = r_base + (n >> 10);
        int d = n & 1023;
        float bias = b1v[r * H_SZ + d];
#pragma unroll
        for (int jj = 0; jj < 4; ++jj) {
          float v = fmaxf(a[jj] + bias, 0.f) * comb[(size_t)(m0 + jj) * 16 + r];
          Hp[(size_t)(m0 + jj) * ldh + n] = f2bf(v);
        }
      } else {
#pragma unroll
        for (int jj = 0; jj < 4; ++jj) {
          size_t row = (size_t)(m0 + jj);
          float v = a[jj];
          if (accum) {
            v += Out[row * H_SZ + n];
          } else {
            float bs = 0.f;
#pragma unroll
            for (int r = 0; r < 16; ++r)
              bs += comb[row * 16 + r] * b2v[r * H_SZ + n];
            v += bs;
          }
          Out[row * H_SZ + n] = v;
        }
      }
    }
  }
}
#undef RDA
#undef RDB
#undef MF
#undef LGKM0

// ======= g2s_gemm: GEMM2 — R12-verified gemm_nt body (128x128, 4 waves, 2-phase, =======
// reg-staged, 2 blocks/CU) with ONLY the block-index mapping changed:
// grid 512 (1-D); bm0 = (id%64)*128, bn0 = (id/64)*128. The 8 blocks sharing an
// Hp m-panel have ids byl+64k -> same id%8 -> same XCD (validated R15/R16:
// FETCH 543->~200 MB); all 512 blocks co-resident (2/CU -> TLP covers staging).
// Out[m,n] = acc + (accum ? Out[m,n] : sum_r comb[m,r]*b2[r,n])
__global__ __launch_bounds__(256) void g2s_gemm(
    const unsigned short* __restrict__ A, int lda,   // Hp group [8192][K]
    const unsigned short* __restrict__ B, int ldb,   // W2T (group col offset applied)
    int K,
    float* __restrict__ Out,
    const float* __restrict__ b2v,
    const float* __restrict__ comb,
    int accum) {
  __shared__ short smem[16384];
  short* As = smem;
  short* Bs = smem + 8192;

  const int tid = threadIdx.x;
  const int lane = tid & 63;
  const int wid = tid >> 6;
  const int wm = wid >> 1, wn = wid & 1;
  const int lr = lane >> 4, lc = lane & 15;

  // XCD-locality mapping (bijective on [0,512))
  const int id = blockIdx.x;
  const int bm0 = (id & 63) * 128;
  const int bn0 = (id >> 6) * 128;

  int srow[4], ssc[4];
#pragma unroll
  for (int i = 0; i < 4; ++i) {
    int idx = i * 256 + tid;
    srow[i] = idx >> 3;
    ssc[i] = idx & 7;
  }

  const f32x4 zero = {0.f, 0.f, 0.f, 0.f};
  f32x4 acc[4][4];
#pragma unroll
  for (int i = 0; i < 4; ++i)
#pragma unroll
    for (int j = 0; j < 4; ++j) acc[i][j] = zero;

  const int KT = K >> 6;

  short8 va[4], vb[4];
#pragma unroll
  for (int i = 0; i < 4; ++i) {
    va[i] = *(const short8*)(A + (size_t)(bm0 + srow[i]) * lda + ssc[i] * 8);
    vb[i] = *(const short8*)(B + (size_t)(bn0 + srow[i]) * ldb + ssc[i] * 8);
  }

  for (int kt = 0; kt < KT; ++kt) {
    __syncthreads();
#pragma unroll
    for (int i = 0; i < 4; ++i) {
      *(short8*)(As + srow[i] * 64 + ((ssc[i] ^ (srow[i] & 7)) * 8)) = va[i];
      *(short8*)(Bs + srow[i] * 64 + ((ssc[i] ^ (srow[i] & 7)) * 8)) = vb[i];
    }
    __syncthreads();
    if (kt + 1 < KT) {
      int k0 = (kt + 1) << 6;
#pragma unroll
      for (int i = 0; i < 4; ++i) {
        va[i] = *(const short8*)(A + (size_t)(bm0 + srow[i]) * lda + k0 + ssc[i] * 8);
        vb[i] = *(const short8*)(B + (size_t)(bn0 + srow[i]) * ldb + k0 + ssc[i] * 8);
      }
    }
#pragma unroll
    for (int c = 0; c < 2; ++c) {
      short8 af[4], bfr[4];
#pragma unroll
      for (int f = 0; f < 4; ++f) {
        int ra = wm * 64 + f * 16 + lc;
        af[f] = *(const short8*)(As + ra * 64 + (((c * 4 + lr) ^ (ra & 7)) * 8));
        int rb = wn * 64 + f * 16 + lc;
        bfr[f] = *(const short8*)(Bs + rb * 64 + (((c * 4 + lr) ^ (rb & 7)) * 8));
      }
#pragma unroll
      for (int mf = 0; mf < 4; ++mf)
#pragma unroll
        for (int nf = 0; nf < 4; ++nf)
          acc[mf][nf] = __builtin_amdgcn_mfma_f32_16x16x32_bf16(af[mf], bfr[nf],
                                                                acc[mf][nf], 0, 0, 0);
    }
  }

  // epilogue: C/D layout col=lane&15, row=(lane>>4)*4+reg
#pragma unroll
  for (int mf = 0; mf < 4; ++mf) {
#pragma unroll
    for (int nf = 0; nf < 4; ++nf) {
      int m0 = bm0 + wm * 64 + mf * 16 + lr * 4;
      int n = bn0 + wn * 64 + nf * 16 + lc;
      f32x4 a = acc[mf][nf];
#pragma unroll
      for (int j = 0; j < 4; ++j) {
        size_t row = (size_t)(m0 + j);
        float v = a[j];
        if (accum) {
          v += Out[row * H_SZ + n];
        } else {
          float bs = 0.f;
#pragma unroll
          for (int r = 0; r < 16; ++r)
            bs += comb[row * 16 + r] * b2v[r * H_SZ + n];
          v += bs;
        }
        Out[row * H_SZ + n] = v;
      }
    }
  }
}

extern "C" void kernel_launch(void* const* d_in, const int* in_sizes, int n_in,
                              void* d_out, int out_size, void* d_ws, size_t ws_size,
                              hipStream_t stream) {
  if (n_in < 9) return;
  const float* x  = (const float*)d_in[0];
  const float* Wa = (const float*)d_in[1];
  const float* ba = (const float*)d_in[2];
  const float* W1 = (const float*)d_in[3];
  const float* b1 = (const float*)d_in[4];
  const float* W2 = (const float*)d_in[5];
  const float* b2 = (const float*)d_in[6];
  const float* Wc = (const float*)d_in[7];
  const float* bc = (const float*)d_in[8];

  float* out = (float*)d_out;
  float* conf = out + (size_t)B_SZ * H_SZ;

  char* w = (char*)d_ws;
  unsigned short* xb = (unsigned short*)w;  w += (size_t)B_SZ * H_SZ * 2;
  unsigned short* W1T = (unsigned short*)w; w += (size_t)R_SZ * H_SZ * H_SZ * 2;
  unsigned short* W2T = (unsigned short*)w; w += (size_t)R_SZ * H_SZ * H_SZ * 2;
  float* comb = (float*)w;                  w += (size_t)B_SZ * R_SZ * 4;
  float* WaT = (float*)w;                   w += (size_t)R_SZ * H_SZ * 4;
  unsigned short* Hp = (unsigned short*)w;
  size_t used = (size_t)(w - (char*)d_ws);

  // largest rule-group size G whose Hp fits (measured: ws gives G=8, ngroups=2)
  int G = 16;
  while (G > 1 && used + (size_t)B_SZ * G * H_SZ * 2 > ws_size) G >>= 1;
  if (used + (size_t)B_SZ * G * H_SZ * 2 > ws_size) return;  // ws too small

  dim3 tb(32, 8);
  tck_transpose<<<dim3(32, 32, 16), tb, 0, stream>>>(W1, W1T, H_SZ, H_SZ);
  tck_transpose<<<dim3(32, 512, 1), tb, 0, stream>>>(W2, W2T, R_SZ * H_SZ, H_SZ);
  twk_transpose_wa<<<dim3(64), dim3(256), 0, stream>>>(Wa, WaT);
  gk_gate<<<dim3(B_SZ / 4), dim3(256), 0, stream>>>(x, WaT, ba, Wc, bc, comb, conf, xb);

  int ngroups = R_SZ / G;
  for (int g = 0; g < ngroups; ++g) {
    // GEMM1 (8-phase m201 protocol, R10-verified): Hp = comb * relu(x @ W1[group] + b1)
    g1k_gemm8<0><<<dim3(G * H_SZ / 256, B_SZ / 256), dim3(512), 0, stream>>>(
        xb, H_SZ,
        W1T + (size_t)g * G * H_SZ * H_SZ, H_SZ, H_SZ,
        Hp, G * H_SZ, b1, nullptr, nullptr, comb, g * G, 0);
    // GEMM2 (R12-verified 2-phase body + XCD-locality mapping, 2 blocks/CU TLP):
    //   out (+)= Hp @ W2[group] (+ gated b2 on g=0)
    g2s_gemm<<<dim3(512), dim3(256), 0, stream>>>(
        Hp, G * H_SZ,
        W2T + (size_t)g * G * H_SZ, R_SZ * H_SZ, G * H_SZ,
        out, b2, comb, (g > 0) ? 1 : 0);
  }
}